// Round 13
// baseline (112.045 us; speedup 1.0000x reference)
//
#include <hip/hip_runtime.h>

typedef unsigned short u16;
typedef unsigned int u32;
typedef __attribute__((ext_vector_type(8))) short bf16x8;
typedef __attribute__((ext_vector_type(4))) float f32x4;
typedef __attribute__((ext_vector_type(16))) float f32x16;

#define LOG2E 1.4426950408889634f

__device__ __forceinline__ u16 f2b(float f) {
  union { float f; u32 u; } v; v.f = f;
  u32 r = v.u + 0x7FFFu + ((v.u >> 16) & 1u);
  return (u16)(r >> 16);
}
__device__ __forceinline__ float b2f(u16 b) {
  union { u32 u; float f; } v; v.u = ((u32)b) << 16;
  return v.f;
}
// pack two f32 -> one u32 holding 2 bf16 (RNE), single HW instr
__device__ __forceinline__ u32 pk2(float lo, float hi) {
  u32 r;
  asm("v_cvt_pk_bf16_f32 %0, %1, %2" : "=v"(r) : "v"(lo), "v"(hi));
  return r;
}
// 2^x / 1/x via compiler-visible TRANS intrinsics (NOT inline asm: TRANS ops
// need wait-states before dependent reads; asm hides that from the hazard
// recognizer — R9 failure). Domain |x| <~ 40 >> -126, so exact vs exp2f.
__device__ __forceinline__ float ex2(float x) { return __builtin_amdgcn_exp2f(x); }
__device__ __forceinline__ float rcp(float x) { return __builtin_amdgcn_rcpf(x); }

__device__ __forceinline__ void gload16(const void* g, void* l) {
  __builtin_amdgcn_global_load_lds(
      (const __attribute__((address_space(1))) u32*)g,
      (__attribute__((address_space(3))) u32*)l, 16, 0, 0);
}

__device__ __forceinline__ f32x16 mfma32(bf16x8 a, bf16x8 b, f32x16 c) {
  return __builtin_amdgcn_mfma_f32_32x32x16_bf16(a, b, c, 0, 0, 0);
}

// ---------------- merged f32 -> bf16 convert (3 segments, 1 launch) --------
__global__ __launch_bounds__(256) void k_cvt3(
    const float* __restrict__ s0, u16* __restrict__ d0, int n0,
    const float* __restrict__ s1, u16* __restrict__ d1, int n1,
    const float* __restrict__ s2, u16* __restrict__ d2, int n2) {
  int i = blockIdx.x * 256 + threadIdx.x;
  const int stride = gridDim.x * 256;
  const int total = n0 + n1 + n2;
  for (; i < total; i += stride) {
    const float4* s; ushort4* d; int j = i;
    if (j < n0)              { s = (const float4*)s0; d = (ushort4*)d0; }
    else if ((j -= n0) < n1) { s = (const float4*)s1; d = (ushort4*)d1; }
    else { j -= n1;            s = (const float4*)s2; d = (ushort4*)d2; }
    float4 v = s[j];
    ushort4 o;
    o.x = f2b(v.x); o.y = f2b(v.y); o.z = f2b(v.z); o.w = f2b(v.w);
    d[j] = o;
  }
}

// ---------------- GEMM: C[m,n] = sum_k A[m,k]*Bw[n,k] (+bias) ----------------
// BM=128 fixed; BN template. __syncthreads() implicitly drains vmcnt before
// its barrier -> cross-wave global_load_lds publication is sound.
template<int OUTMODE, int BN>  // OUTMODE 0: bf16 out; 1: f32 out + bias
__global__ __launch_bounds__(256, 4) void k_gemm_bt(
    const u16* __restrict__ A, const u16* __restrict__ Bw,
    void* __restrict__ Cout, const float* __restrict__ bias,
    int M, int N, int K) {
  constexpr int NT = BN / 32;          // 16-col tiles per wave half
  constexpr int BCH = BN / 32;         // B staging chunks per thread
  __shared__ __align__(16) u16 As[128 * 64];
  __shared__ __align__(16) u16 Bs[BN * 64];
  const int tid = threadIdx.x;
  const int lane = tid & 63, w = tid >> 6;
  const int wr = w >> 1, wc = w & 1;
  const int g = lane >> 4, r16 = lane & 15, l7 = lane & 7;
  const int bm = blockIdx.y, bn = blockIdx.x;
  const int co[2] = { (g ^ l7) * 8, ((4 | g) ^ l7) * 8 };

  f32x4 acc[4][NT] = {};
  const int LCl = w * 64 + lane;

  for (int k0 = 0; k0 < K; k0 += 64) {
    __syncthreads();
#pragma unroll
    for (int i = 0; i < 4; ++i) {
      int LC = i * 256 + LCl;
      int row = LC >> 3;
      int c = (LC & 7) ^ (row & 7);
      gload16(A + (bm * 128 + row) * K + k0 + c * 8, As + (i * 256 + w * 64) * 8);
    }
#pragma unroll
    for (int i = 0; i < BCH; ++i) {
      int LC = i * 256 + LCl;
      int row = LC >> 3;
      int c = (LC & 7) ^ (row & 7);
      gload16(Bw + (bn * BN + row) * K + k0 + c * 8, Bs + (i * 256 + w * 64) * 8);
    }
    __syncthreads();
#pragma unroll
    for (int s = 0; s < 2; ++s) {
      bf16x8 af[4], bfr[NT];
#pragma unroll
      for (int t = 0; t < 4; ++t)
        af[t] = *(const bf16x8*)&As[(wr * 64 + t * 16 + r16) * 64 + co[s]];
#pragma unroll
      for (int t = 0; t < NT; ++t)
        bfr[t] = *(const bf16x8*)&Bs[(wc * (BN / 2) + t * 16 + r16) * 64 + co[s]];
#pragma unroll
      for (int mt = 0; mt < 4; ++mt)
#pragma unroll
        for (int nt = 0; nt < NT; ++nt)
          acc[mt][nt] = __builtin_amdgcn_mfma_f32_16x16x32_bf16(
              af[mt], bfr[nt], acc[mt][nt], 0, 0, 0);
    }
  }

  const int mbase = bm * 128 + wr * 64 + g * 4;
  const int nbase = bn * BN + wc * (BN / 2) + r16;
  if (OUTMODE == 0) {
    u16* C = (u16*)Cout;
#pragma unroll
    for (int mt = 0; mt < 4; ++mt)
#pragma unroll
      for (int nt = 0; nt < NT; ++nt)
#pragma unroll
        for (int r = 0; r < 4; ++r)
          C[(mbase + mt * 16 + r) * N + nbase + nt * 16] = f2b(acc[mt][nt][r]);
  } else {
    float* C = (float*)Cout;
    float bv[NT];
#pragma unroll
    for (int nt = 0; nt < NT; ++nt) bv[nt] = bias[nbase + nt * 16];
#pragma unroll
    for (int mt = 0; mt < 4; ++mt)
#pragma unroll
      for (int nt = 0; nt < NT; ++nt)
#pragma unroll
        for (int r = 0; r < 4; ++r)
          C[(mbase + mt * 16 + r) * N + nbase + nt * 16] = acc[mt][nt][r] + bv[nt];
  }
}

// ---------------- RoPE + layout reorg ----------------
__global__ __launch_bounds__(256) void k_reorg(const u16* __restrict__ qkv,
    u16* __restrict__ Q, u16* __restrict__ K, u16* __restrict__ Vt) {
  __shared__ u16 vsh[64 * 72];
  const int bh = blockIdx.y, nt = blockIdx.x;
  const int b = bh >> 4, h = bh & 15;
  const int tid = threadIdx.x;
  const int nl = tid >> 2, c4 = tid & 3;
  const int n = nt * 64 + nl;
  const int srow = (b * 2048 + n) * 3072 + h * 64 + c4 * 16;

  float cs[8], sn[8];
#pragma unroll
  for (int p = 0; p < 8; ++p) {
    int c = c4 * 8 + p;
    float invf = exp2f(-0.41524101186092035f * (float)c);  // 10000^(-2c/64)
    float ang = (float)n * invf;
    sincosf(ang, &sn[p], &cs[p]);
  }

#pragma unroll
  for (int sel = 0; sel < 2; ++sel) {
    union { uint4 v[2]; u16 s[16]; } in, out;
    const uint4* sp = (const uint4*)(qkv + srow + sel * 1024);
    in.v[0] = sp[0]; in.v[1] = sp[1];
    const float scale = sel ? 1.0f : (0.125f * LOG2E);
#pragma unroll
    for (int p = 0; p < 8; ++p) {
      float xe = b2f(in.s[2 * p]), xo = b2f(in.s[2 * p + 1]);
      out.s[2 * p]     = f2b((xe * cs[p] - xo * sn[p]) * scale);
      out.s[2 * p + 1] = f2b((xe * sn[p] + xo * cs[p]) * scale);
    }
    u16* dp = (sel ? K : Q) + (bh * 2048 + n) * 64 + c4 * 16;
    ((uint4*)dp)[0] = out.v[0];
    ((uint4*)dp)[1] = out.v[1];
  }

  {
    const uint4* sp = (const uint4*)(qkv + srow + 2048);
    uint4 v0 = sp[0], v1 = sp[1];
    *(uint4*)&vsh[nl * 72 + c4 * 16] = v0;
    *(uint4*)&vsh[nl * 72 + c4 * 16 + 8] = v1;
  }
  __syncthreads();
  {
    const int d = tid >> 2, nc = tid & 3;
    union { uint4 v[2]; u16 s[16]; } o;
#pragma unroll
    for (int j = 0; j < 16; ++j) o.s[j] = vsh[(nc * 16 + j) * 72 + d];
    u16* dp = Vt + (bh * 64 + d) * 2048 + nt * 64 + nc * 16;
    ((uint4*)dp)[0] = o.v[0];
    ((uint4*)dp)[1] = o.v[1];
  }
}

// ---------------- Flash attention, 32x32 MFMA, kv-split waves ----------------
// TRIPLE-buffered K/V with counted vmcnt (T3/T4): per iter = stage(it+2) ->
// compute(it) -> s_waitcnt vmcnt(4) -> s_barrier. The waited loads (stage
// it+1) were issued a FULL iteration (~900+ cyc) earlier, so the HBM latency
// is covered — unlike the R12 double-buffer whose same-iter vmcnt(0) drain
// stalled all waves ~300 cyc/iter (measured as the missing 33% issue).
// Race-soundness (R10 lesson): drain precedes barrier; stage target buffer
// (it+2)%3 was last read at it-1 whose readers passed the end-of-(it-1)
// barrier before this iter's stage issues.
__global__ __launch_bounds__(256, 3) void k_attn(
    const u16* __restrict__ Q, const u16* __restrict__ K,
    const u16* __restrict__ Vt, u16* __restrict__ Ao) {
  __shared__ __align__(16) u16 SH[6][64 * 64];  // [0..2] K tribuf, [3..5] V tribuf
  const int tid = threadIdx.x;
  const int lane = tid & 63, w = tid >> 6;
  const int l31 = lane & 31, hi = lane >> 5;
  const int qpair = w >> 1, kvh = w & 1;
  const int bh = blockIdx.y, qt = blockIdx.x;
  const int rr = l31 & 7;
  const int u = hi ^ (rr & 1);
  const int v = (rr >> 1) & 3;

  const int qrow = qt * 64 + qpair * 32 + l31;
  const u16* Qb = Q + (bh * 2048 + qrow) * 64 + 8 * hi;
  bf16x8 qf[4];
#pragma unroll
  for (int ks = 0; ks < 4; ++ks) qf[ks] = *(const bf16x8*)(Qb + 16 * ks);

  float z0 = 0.f;
  asm volatile("" : "+v"(z0));
  f32x16 zv;
#pragma unroll
  for (int r = 0; r < 16; ++r) zv[r] = z0;

  const u16 *kg0, *kg1, *vg0, *vg1;
  {
    int LC = tid, row = LC >> 3, c = (LC & 7) ^ (row & 7);
    kg0 = K + (bh * 2048 + row) * 64 + c * 8;
    vg0 = Vt + (bh * 64 + row) * 2048 + c * 8;
    int LC1 = 256 + tid, row1 = LC1 >> 3, c1 = (LC1 & 7) ^ (row1 & 7);
    kg1 = K + (bh * 2048 + row1) * 64 + c1 * 8;
    vg1 = Vt + (bh * 64 + row1) * 2048 + c1 * 8;
  }

  const int krowK = (kvh * 32 + l31) * 128;
  const int vrow0 = l31 * 128, vrow1 = (32 + l31) * 128;

  f32x16 acc0 = {}, acc1 = {};
  float lrun = 0.f;

  // prologue: stage tiles 0,1 into bufs 0,1; wait tile 0 (vmcnt 4); publish
#pragma unroll
  for (int t = 0; t < 2; ++t) {
    gload16(kg0, SH[t] + tid * 8);
    gload16(kg1, SH[t] + (256 + tid) * 8);
    gload16(vg0, SH[3 + t] + tid * 8);
    gload16(vg1, SH[3 + t] + (256 + tid) * 8);
    kg0 += 4096; kg1 += 4096; vg0 += 64; vg1 += 64;
  }
  asm volatile("s_waitcnt vmcnt(4)" ::: "memory");
  __builtin_amdgcn_s_barrier();

#define ATTN_STEP(RB, SB, DO_STAGE, WAIT0)                                     \
  do {                                                                         \
    if (DO_STAGE) {                                                            \
      gload16(kg0, SH[SB] + tid * 8);                                          \
      gload16(kg1, SH[SB] + (256 + tid) * 8);                                  \
      gload16(vg0, SH[3 + SB] + tid * 8);                                      \
      gload16(vg1, SH[3 + SB] + (256 + tid) * 8);                              \
      kg0 += 4096; kg1 += 4096; vg0 += 64; vg1 += 64;                          \
    }                                                                          \
    const char* Kb = (const char*)SH[RB];                                      \
    const char* Vb = (const char*)SH[3 + RB];                                  \
    f32x16 st;                                                                 \
    __builtin_amdgcn_s_setprio(1);                                             \
    {                                                                          \
      const int coff = (2 * v + u) << 4;                                       \
      bf16x8 ka = *(const bf16x8*)(Kb + krowK + coff);                         \
      st = mfma32(ka, qf[0], zv);                                              \
    }                                                                          \
    _Pragma("unroll")                                                          \
    for (int ks = 1; ks < 4; ++ks) {                                           \
      const int coff = (2 * (ks ^ v) + u) << 4;                                \
      bf16x8 ka = *(const bf16x8*)(Kb + krowK + coff);                         \
      st = mfma32(ka, qf[ks], st);                                             \
    }                                                                          \
    __builtin_amdgcn_s_setprio(0);                                             \
    float ls[4];                                                               \
    u32 W[4][2];                                                               \
    _Pragma("unroll")                                                          \
    for (int s = 0; s < 4; ++s) {                                              \
      float pa = ex2(st[4 * s + 0]);                                           \
      float pb = ex2(st[4 * s + 1]);                                           \
      float pc = ex2(st[4 * s + 2]);                                           \
      float pd = ex2(st[4 * s + 3]);                                           \
      ls[s] = (pa + pb) + (pc + pd);                                           \
      W[s][0] = pk2(pa, pb);                                                   \
      W[s][1] = pk2(pc, pd);                                                   \
    }                                                                          \
    lrun += (ls[0] + ls[1]) + (ls[2] + ls[3]);                                 \
    __builtin_amdgcn_s_setprio(1);                                             \
    _Pragma("unroll")                                                          \
    for (int ku = 0; ku < 2; ++ku) {                                           \
      u32 a0 = W[2 * ku][0], b0 = W[2 * ku + 1][0];                            \
      u32 a1 = W[2 * ku][1], b1 = W[2 * ku + 1][1];                            \
      asm volatile("v_permlane32_swap_b32 %0, %1" : "+&v"(a0), "+v"(b0));      \
      asm volatile("v_permlane32_swap_b32 %0, %1" : "+&v"(a1), "+v"(b1));      \
      union { u32 wd[4]; bf16x8 v8; } pbu;                                     \
      pbu.wd[0] = a0; pbu.wd[1] = a1; pbu.wd[2] = b0; pbu.wd[3] = b1;          \
      const int j = 2 * kvh + ku;                                              \
      const int coff = (2 * (j ^ v) + u) << 4;                                 \
      bf16x8 va0 = *(const bf16x8*)(Vb + vrow0 + coff);                        \
      bf16x8 va1 = *(const bf16x8*)(Vb + vrow1 + coff);                        \
      acc0 = mfma32(va0, pbu.v8, acc0);                                        \
      acc1 = mfma32(va1, pbu.v8, acc1);                                        \
    }                                                                          \
    __builtin_amdgcn_s_setprio(0);                                             \
    if (WAIT0) asm volatile("s_waitcnt vmcnt(0)" ::: "memory");                \
    else       asm volatile("s_waitcnt vmcnt(4)" ::: "memory");                \
    __builtin_amdgcn_s_barrier();                                              \
  } while (0)

#pragma unroll 1
  for (int base = 0; base < 30; base += 3) {
    ATTN_STEP(0, 2, 1, 0);
    ATTN_STEP(1, 0, 1, 0);
    ATTN_STEP(2, 1, 1, 0);
  }
  ATTN_STEP(0, 2, 0, 1);  // it=30: no stage; drain stage(31) fully
  ATTN_STEP(1, 0, 0, 1);  // it=31: nothing outstanding; final barrier kept
#undef ATTN_STEP

  // ---- epilogue: reduce the two kv-half waves of each qpair via LDS ----
  float* FS = (float*)SH;
  const int sbase = (qpair * 64 + lane) * 33;
  if (kvh == 1) {
#pragma unroll
    for (int r = 0; r < 16; ++r) {
      FS[sbase + r] = acc0[r];
      FS[sbase + 16 + r] = acc1[r];
    }
    FS[8000 + qpair * 64 + lane] = lrun;
  }
  __syncthreads();
  if (kvh == 0) {
#pragma unroll
    for (int r = 0; r < 16; ++r) {
      acc0[r] += FS[sbase + r];
      acc1[r] += FS[sbase + 16 + r];
    }
    lrun += FS[8000 + qpair * 64 + lane];
    float lo = __shfl_xor(lrun, 32);
    float sc = rcp(lrun + lo);

    const int m = (bh >> 4) * 2048 + qrow;
    u16* orow = Ao + m * 1024 + (bh & 15) * 64 + 4 * hi;
#pragma unroll
    for (int s = 0; s < 4; ++s) {
      uint2 o0, o1;
      o0.x = pk2(acc0[4 * s + 0] * sc, acc0[4 * s + 1] * sc);
      o0.y = pk2(acc0[4 * s + 2] * sc, acc0[4 * s + 3] * sc);
      *(uint2*)(orow + 8 * s) = o0;
      o1.x = pk2(acc1[4 * s + 0] * sc, acc1[4 * s + 1] * sc);
      o1.y = pk2(acc1[4 * s + 2] * sc, acc1[4 * s + 3] * sc);
      *(uint2*)(orow + 32 + 8 * s) = o1;
    }
  }
}

extern "C" void kernel_launch(void* const* d_in, const int* in_sizes, int n_in,
                              void* d_out, int out_size, void* d_ws, size_t ws_size,
                              hipStream_t stream) {
  (void)in_sizes; (void)n_in; (void)out_size; (void)ws_size;
  const float* x      = (const float*)d_in[0];
  const float* w_qkv  = (const float*)d_in[1];
  const float* w_proj = (const float*)d_in[2];
  const float* b_proj = (const float*)d_in[3];
  float* out = (float*)d_out;

  char* W = (char*)d_ws;
  u16* xb     = (u16*)(W + 0);              // 4096x1024 bf16 (8 MB)
  u16* attnb  = (u16*)(W + 0);              // reuse xb region after GEMM1
  u16* wqkvb  = (u16*)(W + (8u  << 20));    // 3072x1024 bf16 (6 MB)
  u16* wprojb = (u16*)(W + (14u << 20));    // 1024x1024 bf16 (2 MB)
  u16* qkvb   = (u16*)(W + (16u << 20));    // 4096x3072 bf16 (24 MB)
  u16* Qws    = (u16*)(W + (40u << 20));    // 32x2048x64 bf16 (8 MB)
  u16* Kws    = (u16*)(W + (48u << 20));    // 32x2048x64 bf16 (8 MB)
  u16* Vtws   = (u16*)(W + (56u << 20));    // 32x64x2048 bf16 (8 MB)

  k_cvt3<<<2048, 256, 0, stream>>>(x, xb, (4096 * 1024) / 4,
                                   w_qkv, wqkvb, (3072 * 1024) / 4,
                                   w_proj, wprojb, (1024 * 1024) / 4);
  k_gemm_bt<0, 96><<<dim3(32, 32), 256, 0, stream>>>(
      xb, wqkvb, (void*)qkvb, nullptr, 4096, 3072, 1024);
  k_reorg<<<dim3(32, 32), 256, 0, stream>>>(qkvb, Qws, Kws, Vtws);
  k_attn<<<dim3(32, 32), 256, 0, stream>>>(Qws, Kws, Vtws, attnb);
  k_gemm_bt<1, 32><<<dim3(32, 32), 256, 0, stream>>>(
      attnb, wprojb, (void*)out, b_proj, 4096, 1024, 1024);
}

// Round 15
// 111.101 us; speedup vs baseline: 1.0085x; 1.0085x over previous
//
#include <hip/hip_runtime.h>

typedef unsigned short u16;
typedef unsigned int u32;
typedef __attribute__((ext_vector_type(8))) short bf16x8;
typedef __attribute__((ext_vector_type(4))) float f32x4;
typedef __attribute__((ext_vector_type(16))) float f32x16;

#define LOG2E 1.4426950408889634f

__device__ __forceinline__ u16 f2b(float f) {
  union { float f; u32 u; } v; v.f = f;
  u32 r = v.u + 0x7FFFu + ((v.u >> 16) & 1u);
  return (u16)(r >> 16);
}
__device__ __forceinline__ float b2f(u16 b) {
  union { u32 u; float f; } v; v.u = ((u32)b) << 16;
  return v.f;
}
// pack two f32 -> one u32 holding 2 bf16 (RNE), single HW instr
__device__ __forceinline__ u32 pk2(float lo, float hi) {
  u32 r;
  asm("v_cvt_pk_bf16_f32 %0, %1, %2" : "=v"(r) : "v"(lo), "v"(hi));
  return r;
}
// 2^x / 1/x via compiler-visible TRANS intrinsics (NOT inline asm: TRANS ops
// need wait-states before dependent reads; asm hides that from the hazard
// recognizer — R9 failure). Domain |x| <~ 40 >> -126, so exact vs exp2f.
__device__ __forceinline__ float ex2(float x) { return __builtin_amdgcn_exp2f(x); }
__device__ __forceinline__ float rcp(float x) { return __builtin_amdgcn_rcpf(x); }

__device__ __forceinline__ void gload16(const void* g, void* l) {
  __builtin_amdgcn_global_load_lds(
      (const __attribute__((address_space(1))) u32*)g,
      (__attribute__((address_space(3))) u32*)l, 16, 0, 0);
}

__device__ __forceinline__ f32x16 mfma32(bf16x8 a, bf16x8 b, f32x16 c) {
  return __builtin_amdgcn_mfma_f32_32x32x16_bf16(a, b, c, 0, 0, 0);
}

// ---------------- merged f32 -> bf16 convert (3 segments, 1 launch) --------
__global__ __launch_bounds__(256) void k_cvt3(
    const float* __restrict__ s0, u16* __restrict__ d0, int n0,
    const float* __restrict__ s1, u16* __restrict__ d1, int n1,
    const float* __restrict__ s2, u16* __restrict__ d2, int n2) {
  int i = blockIdx.x * 256 + threadIdx.x;
  const int stride = gridDim.x * 256;
  const int total = n0 + n1 + n2;
  for (; i < total; i += stride) {
    const float4* s; ushort4* d; int j = i;
    if (j < n0)              { s = (const float4*)s0; d = (ushort4*)d0; }
    else if ((j -= n0) < n1) { s = (const float4*)s1; d = (ushort4*)d1; }
    else { j -= n1;            s = (const float4*)s2; d = (ushort4*)d2; }
    float4 v = s[j];
    ushort4 o;
    o.x = f2b(v.x); o.y = f2b(v.y); o.z = f2b(v.z); o.w = f2b(v.w);
    d[j] = o;
  }
}

// ---------------- GEMM: C[m,n] = sum_k A[m,k]*Bw[n,k] (+bias) ----------------
// BM=128 fixed; BN template. __syncthreads() implicitly drains vmcnt before
// its barrier -> cross-wave global_load_lds publication is sound.
template<int OUTMODE, int BN>  // OUTMODE 0: bf16 out; 1: f32 out + bias
__global__ __launch_bounds__(256, 4) void k_gemm_bt(
    const u16* __restrict__ A, const u16* __restrict__ Bw,
    void* __restrict__ Cout, const float* __restrict__ bias,
    int M, int N, int K) {
  constexpr int NT = BN / 32;          // 16-col tiles per wave half
  constexpr int BCH = BN / 32;         // B staging chunks per thread
  __shared__ __align__(16) u16 As[128 * 64];
  __shared__ __align__(16) u16 Bs[BN * 64];
  const int tid = threadIdx.x;
  const int lane = tid & 63, w = tid >> 6;
  const int wr = w >> 1, wc = w & 1;
  const int g = lane >> 4, r16 = lane & 15, l7 = lane & 7;
  const int bm = blockIdx.y, bn = blockIdx.x;
  const int co[2] = { (g ^ l7) * 8, ((4 | g) ^ l7) * 8 };

  f32x4 acc[4][NT] = {};
  const int LCl = w * 64 + lane;

  for (int k0 = 0; k0 < K; k0 += 64) {
    __syncthreads();
#pragma unroll
    for (int i = 0; i < 4; ++i) {
      int LC = i * 256 + LCl;
      int row = LC >> 3;
      int c = (LC & 7) ^ (row & 7);
      gload16(A + (bm * 128 + row) * K + k0 + c * 8, As + (i * 256 + w * 64) * 8);
    }
#pragma unroll
    for (int i = 0; i < BCH; ++i) {
      int LC = i * 256 + LCl;
      int row = LC >> 3;
      int c = (LC & 7) ^ (row & 7);
      gload16(Bw + (bn * BN + row) * K + k0 + c * 8, Bs + (i * 256 + w * 64) * 8);
    }
    __syncthreads();
#pragma unroll
    for (int s = 0; s < 2; ++s) {
      bf16x8 af[4], bfr[NT];
#pragma unroll
      for (int t = 0; t < 4; ++t)
        af[t] = *(const bf16x8*)&As[(wr * 64 + t * 16 + r16) * 64 + co[s]];
#pragma unroll
      for (int t = 0; t < NT; ++t)
        bfr[t] = *(const bf16x8*)&Bs[(wc * (BN / 2) + t * 16 + r16) * 64 + co[s]];
#pragma unroll
      for (int mt = 0; mt < 4; ++mt)
#pragma unroll
        for (int nt = 0; nt < NT; ++nt)
          acc[mt][nt] = __builtin_amdgcn_mfma_f32_16x16x32_bf16(
              af[mt], bfr[nt], acc[mt][nt], 0, 0, 0);
    }
  }

  const int mbase = bm * 128 + wr * 64 + g * 4;
  const int nbase = bn * BN + wc * (BN / 2) + r16;
  if (OUTMODE == 0) {
    u16* C = (u16*)Cout;
#pragma unroll
    for (int mt = 0; mt < 4; ++mt)
#pragma unroll
      for (int nt = 0; nt < NT; ++nt)
#pragma unroll
        for (int r = 0; r < 4; ++r)
          C[(mbase + mt * 16 + r) * N + nbase + nt * 16] = f2b(acc[mt][nt][r]);
  } else {
    float* C = (float*)Cout;
    float bv[NT];
#pragma unroll
    for (int nt = 0; nt < NT; ++nt) bv[nt] = bias[nbase + nt * 16];
#pragma unroll
    for (int mt = 0; mt < 4; ++mt)
#pragma unroll
      for (int nt = 0; nt < NT; ++nt)
#pragma unroll
        for (int r = 0; r < 4; ++r)
          C[(mbase + mt * 16 + r) * N + nbase + nt * 16] = acc[mt][nt][r] + bv[nt];
  }
}

// ---------------- RoPE + layout reorg ----------------
__global__ __launch_bounds__(256) void k_reorg(const u16* __restrict__ qkv,
    u16* __restrict__ Q, u16* __restrict__ K, u16* __restrict__ Vt) {
  __shared__ u16 vsh[64 * 72];
  const int bh = blockIdx.y, nt = blockIdx.x;
  const int b = bh >> 4, h = bh & 15;
  const int tid = threadIdx.x;
  const int nl = tid >> 2, c4 = tid & 3;
  const int n = nt * 64 + nl;
  const int srow = (b * 2048 + n) * 3072 + h * 64 + c4 * 16;

  float cs[8], sn[8];
#pragma unroll
  for (int p = 0; p < 8; ++p) {
    int c = c4 * 8 + p;
    float invf = exp2f(-0.41524101186092035f * (float)c);  // 10000^(-2c/64)
    float ang = (float)n * invf;
    sincosf(ang, &sn[p], &cs[p]);
  }

#pragma unroll
  for (int sel = 0; sel < 2; ++sel) {
    union { uint4 v[2]; u16 s[16]; } in, out;
    const uint4* sp = (const uint4*)(qkv + srow + sel * 1024);
    in.v[0] = sp[0]; in.v[1] = sp[1];
    const float scale = sel ? 1.0f : (0.125f * LOG2E);
#pragma unroll
    for (int p = 0; p < 8; ++p) {
      float xe = b2f(in.s[2 * p]), xo = b2f(in.s[2 * p + 1]);
      out.s[2 * p]     = f2b((xe * cs[p] - xo * sn[p]) * scale);
      out.s[2 * p + 1] = f2b((xe * sn[p] + xo * cs[p]) * scale);
    }
    u16* dp = (sel ? K : Q) + (bh * 2048 + n) * 64 + c4 * 16;
    ((uint4*)dp)[0] = out.v[0];
    ((uint4*)dp)[1] = out.v[1];
  }

  {
    const uint4* sp = (const uint4*)(qkv + srow + 2048);
    uint4 v0 = sp[0], v1 = sp[1];
    *(uint4*)&vsh[nl * 72 + c4 * 16] = v0;
    *(uint4*)&vsh[nl * 72 + c4 * 16 + 8] = v1;
  }
  __syncthreads();
  {
    const int d = tid >> 2, nc = tid & 3;
    union { uint4 v[2]; u16 s[16]; } o;
#pragma unroll
    for (int j = 0; j < 16; ++j) o.s[j] = vsh[(nc * 16 + j) * 72 + d];
    u16* dp = Vt + (bh * 64 + d) * 2048 + nt * 64 + nc * 16;
    ((uint4*)dp)[0] = o.v[0];
    ((uint4*)dp)[1] = o.v[1];
  }
}

// ---------------- Flash attention, 32x32 MFMA, kv-split waves ----------------
// Sync pattern (RACE LESSON, R10): per iter = stage(it+1) -> compute(it) ->
// s_waitcnt vmcnt(0) -> s_barrier. The vmcnt DRAIN MUST PRECEDE THE BARRIER:
// waves read LDS chunks staged by OTHER waves' async global_load_lds, and
// s_barrier orders instruction streams, not load completion.
// (R13 triple-buffer removed the drain stall but cost a block of occupancy —
// net loss; R14's asymmetric pipeline depended on unverifiable scheduler
// issue-order — broken. This double-buffer config is the verified optimum.)
__global__ __launch_bounds__(256, 4) void k_attn(
    const u16* __restrict__ Q, const u16* __restrict__ K,
    const u16* __restrict__ Vt, u16* __restrict__ Ao) {
  __shared__ __align__(16) u16 SH[4][64 * 64];  // [0..1] K dbuf, [2..3] V dbuf
  const int tid = threadIdx.x;
  const int lane = tid & 63, w = tid >> 6;
  const int l31 = lane & 31, hi = lane >> 5;
  const int qpair = w >> 1, kvh = w & 1;
  const int bh = blockIdx.y, qt = blockIdx.x;
  const int rr = l31 & 7;
  const int u = hi ^ (rr & 1);
  const int v = (rr >> 1) & 3;

  const int qrow = qt * 64 + qpair * 32 + l31;
  const u16* Qb = Q + (bh * 2048 + qrow) * 64 + 8 * hi;
  bf16x8 qf[4];
#pragma unroll
  for (int ks = 0; ks < 4; ++ks) qf[ks] = *(const bf16x8*)(Qb + 16 * ks);

  float z0 = 0.f;
  asm volatile("" : "+v"(z0));
  f32x16 zv;
#pragma unroll
  for (int r = 0; r < 16; ++r) zv[r] = z0;

  const u16 *kg0, *kg1, *vg0, *vg1;
  {
    int LC = tid, row = LC >> 3, c = (LC & 7) ^ (row & 7);
    kg0 = K + (bh * 2048 + row) * 64 + c * 8;
    vg0 = Vt + (bh * 64 + row) * 2048 + c * 8;
    int LC1 = 256 + tid, row1 = LC1 >> 3, c1 = (LC1 & 7) ^ (row1 & 7);
    kg1 = K + (bh * 2048 + row1) * 64 + c1 * 8;
    vg1 = Vt + (bh * 64 + row1) * 2048 + c1 * 8;
  }

  const int krowK = (kvh * 32 + l31) * 128;
  const int vrow0 = l31 * 128, vrow1 = (32 + l31) * 128;

  f32x16 acc0 = {}, acc1 = {};
  float lrun = 0.f;

  // prologue: stage tile 0 into buf 0, drain, publish
  gload16(kg0, SH[0] + tid * 8);
  gload16(kg1, SH[0] + (256 + tid) * 8);
  gload16(vg0, SH[2] + tid * 8);
  gload16(vg1, SH[2] + (256 + tid) * 8);
  kg0 += 4096; kg1 += 4096; vg0 += 64; vg1 += 64;
  asm volatile("s_waitcnt vmcnt(0)" ::: "memory");
  __builtin_amdgcn_s_barrier();

#pragma unroll 2
  for (int it = 0; it < 32; ++it) {
    const int cur = it & 1;
    if (it < 31) {  // issue next-tile stage first; lands under this compute
      gload16(kg0, SH[cur ^ 1] + tid * 8);
      gload16(kg1, SH[cur ^ 1] + (256 + tid) * 8);
      gload16(vg0, SH[2 + (cur ^ 1)] + tid * 8);
      gload16(vg1, SH[2 + (cur ^ 1)] + (256 + tid) * 8);
      kg0 += 4096; kg1 += 4096; vg0 += 64; vg1 += 64;
    }

    const char* Kb = (const char*)SH[cur];
    const char* Vb = (const char*)SH[2 + cur];

    f32x16 st;
    __builtin_amdgcn_s_setprio(1);
    {
      const int coff = (2 * v + u) << 4;
      bf16x8 ka = *(const bf16x8*)(Kb + krowK + coff);
      st = mfma32(ka, qf[0], zv);
    }
#pragma unroll
    for (int ks = 1; ks < 4; ++ks) {
      const int coff = (2 * (ks ^ v) + u) << 4;
      bf16x8 ka = *(const bf16x8*)(Kb + krowK + coff);
      st = mfma32(ka, qf[ks], st);
    }
    __builtin_amdgcn_s_setprio(0);

    float ls[4];
    u32 W[4][2];
#pragma unroll
    for (int s = 0; s < 4; ++s) {
      float pa = ex2(st[4 * s + 0]);
      float pb = ex2(st[4 * s + 1]);
      float pc = ex2(st[4 * s + 2]);
      float pd = ex2(st[4 * s + 3]);
      ls[s] = (pa + pb) + (pc + pd);
      W[s][0] = pk2(pa, pb);
      W[s][1] = pk2(pc, pd);
    }
    lrun += (ls[0] + ls[1]) + (ls[2] + ls[3]);

    __builtin_amdgcn_s_setprio(1);
#pragma unroll
    for (int ku = 0; ku < 2; ++ku) {
      u32 a0 = W[2 * ku][0], b0 = W[2 * ku + 1][0];
      u32 a1 = W[2 * ku][1], b1 = W[2 * ku + 1][1];
      asm volatile("v_permlane32_swap_b32 %0, %1" : "+&v"(a0), "+v"(b0));
      asm volatile("v_permlane32_swap_b32 %0, %1" : "+&v"(a1), "+v"(b1));
      union { u32 wd[4]; bf16x8 v8; } pbu;
      pbu.wd[0] = a0; pbu.wd[1] = a1; pbu.wd[2] = b0; pbu.wd[3] = b1;
      const int j = 2 * kvh + ku;
      const int coff = (2 * (j ^ v) + u) << 4;
      bf16x8 va0 = *(const bf16x8*)(Vb + vrow0 + coff);
      bf16x8 va1 = *(const bf16x8*)(Vb + vrow1 + coff);
      acc0 = mfma32(va0, pbu.v8, acc0);
      acc1 = mfma32(va1, pbu.v8, acc1);
    }
    __builtin_amdgcn_s_setprio(0);

    // drain my stage loads, THEN publish via barrier (race-free ordering)
    asm volatile("s_waitcnt vmcnt(0)" ::: "memory");
    __builtin_amdgcn_s_barrier();
  }

  // ---- epilogue: reduce the two kv-half waves of each qpair via LDS ----
  float* FS = (float*)SH;
  const int sbase = (qpair * 64 + lane) * 33;
  if (kvh == 1) {
#pragma unroll
    for (int r = 0; r < 16; ++r) {
      FS[sbase + r] = acc0[r];
      FS[sbase + 16 + r] = acc1[r];
    }
    FS[8000 + qpair * 64 + lane] = lrun;
  }
  __syncthreads();
  if (kvh == 0) {
#pragma unroll
    for (int r = 0; r < 16; ++r) {
      acc0[r] += FS[sbase + r];
      acc1[r] += FS[sbase + 16 + r];
    }
    lrun += FS[8000 + qpair * 64 + lane];
    float lo = __shfl_xor(lrun, 32);
    float sc = rcp(lrun + lo);

    const int m = (bh >> 4) * 2048 + qrow;
    u16* orow = Ao + m * 1024 + (bh & 15) * 64 + 4 * hi;
#pragma unroll
    for (int s = 0; s < 4; ++s) {
      uint2 o0, o1;
      o0.x = pk2(acc0[4 * s + 0] * sc, acc0[4 * s + 1] * sc);
      o0.y = pk2(acc0[4 * s + 2] * sc, acc0[4 * s + 3] * sc);
      *(uint2*)(orow + 8 * s) = o0;
      o1.x = pk2(acc1[4 * s + 0] * sc, acc1[4 * s + 1] * sc);
      o1.y = pk2(acc1[4 * s + 2] * sc, acc1[4 * s + 3] * sc);
      *(uint2*)(orow + 32 + 8 * s) = o1;
    }
  }
}

extern "C" void kernel_launch(void* const* d_in, const int* in_sizes, int n_in,
                              void* d_out, int out_size, void* d_ws, size_t ws_size,
                              hipStream_t stream) {
  (void)in_sizes; (void)n_in; (void)out_size; (void)ws_size;
  const float* x      = (const float*)d_in[0];
  const float* w_qkv  = (const float*)d_in[1];
  const float* w_proj = (const float*)d_in[2];
  const float* b_proj = (const float*)d_in[3];
  float* out = (float*)d_out;

  char* W = (char*)d_ws;
  u16* xb     = (u16*)(W + 0);              // 4096x1024 bf16 (8 MB)
  u16* attnb  = (u16*)(W + 0);              // reuse xb region after GEMM1
  u16* wqkvb  = (u16*)(W + (8u  << 20));    // 3072x1024 bf16 (6 MB)
  u16* wprojb = (u16*)(W + (14u << 20));    // 1024x1024 bf16 (2 MB)
  u16* qkvb   = (u16*)(W + (16u << 20));    // 4096x3072 bf16 (24 MB)
  u16* Qws    = (u16*)(W + (40u << 20));    // 32x2048x64 bf16 (8 MB)
  u16* Kws    = (u16*)(W + (48u << 20));    // 32x2048x64 bf16 (8 MB)
  u16* Vtws   = (u16*)(W + (56u << 20));    // 32x64x2048 bf16 (8 MB)

  k_cvt3<<<2048, 256, 0, stream>>>(x, xb, (4096 * 1024) / 4,
                                   w_qkv, wqkvb, (3072 * 1024) / 4,
                                   w_proj, wprojb, (1024 * 1024) / 4);
  k_gemm_bt<0, 96><<<dim3(32, 32), 256, 0, stream>>>(
      xb, wqkvb, (void*)qkvb, nullptr, 4096, 3072, 1024);
  k_reorg<<<dim3(32, 32), 256, 0, stream>>>(qkvb, Qws, Kws, Vtws);
  k_attn<<<dim3(32, 32), 256, 0, stream>>>(Qws, Kws, Vtws, attnb);
  k_gemm_bt<1, 32><<<dim3(32, 32), 256, 0, stream>>>(
      attnb, wprojb, (void*)out, b_proj, 4096, 1024, 1024);
}

// Round 16
// 110.702 us; speedup vs baseline: 1.0121x; 1.0036x over previous
//
#include <hip/hip_runtime.h>

typedef unsigned short u16;
typedef unsigned int u32;
typedef __attribute__((ext_vector_type(8))) short bf16x8;
typedef __attribute__((ext_vector_type(4))) float f32x4;
typedef __attribute__((ext_vector_type(16))) float f32x16;

#define LOG2E 1.4426950408889634f

__device__ __forceinline__ u16 f2b(float f) {
  union { float f; u32 u; } v; v.f = f;
  u32 r = v.u + 0x7FFFu + ((v.u >> 16) & 1u);
  return (u16)(r >> 16);
}
__device__ __forceinline__ float b2f(u16 b) {
  union { u32 u; float f; } v; v.u = ((u32)b) << 16;
  return v.f;
}
// pack two f32 -> one u32 holding 2 bf16 (RNE), single HW instr
__device__ __forceinline__ u32 pk2(float lo, float hi) {
  u32 r;
  asm("v_cvt_pk_bf16_f32 %0, %1, %2" : "=v"(r) : "v"(lo), "v"(hi));
  return r;
}
// 2^x / 1/x via compiler-visible TRANS intrinsics (NOT inline asm: TRANS ops
// need wait-states before dependent reads; asm hides that from the hazard
// recognizer — R9 failure). Domain |x| <~ 40 >> -126, so exact vs exp2f.
__device__ __forceinline__ float ex2(float x) { return __builtin_amdgcn_exp2f(x); }
__device__ __forceinline__ float rcp(float x) { return __builtin_amdgcn_rcpf(x); }

__device__ __forceinline__ void gload16(const void* g, void* l) {
  __builtin_amdgcn_global_load_lds(
      (const __attribute__((address_space(1))) u32*)g,
      (__attribute__((address_space(3))) u32*)l, 16, 0, 0);
}

__device__ __forceinline__ f32x16 mfma32(bf16x8 a, bf16x8 b, f32x16 c) {
  return __builtin_amdgcn_mfma_f32_32x32x16_bf16(a, b, c, 0, 0, 0);
}

// XCD-aware chunked swizzle (T1): hardware round-robins linear block ids
// across the 8 XCDs; this remap gives each XCD a CONTIGUOUS chunk of the
// logical work so per-XCD L2 working sets shrink (attn: 4 bh's K/V+Q = 4MB
// instead of all 32). Bijective because nwg % 8 == 0 (1024 = 8 * 128).
__device__ __forceinline__ int xcd_swz(int lid, int nwg) {
  return (lid & 7) * (nwg >> 3) + (lid >> 3);
}

// ---------------- merged f32 -> bf16 convert (3 segments, 1 launch) --------
__global__ __launch_bounds__(256) void k_cvt3(
    const float* __restrict__ s0, u16* __restrict__ d0, int n0,
    const float* __restrict__ s1, u16* __restrict__ d1, int n1,
    const float* __restrict__ s2, u16* __restrict__ d2, int n2) {
  int i = blockIdx.x * 256 + threadIdx.x;
  const int stride = gridDim.x * 256;
  const int total = n0 + n1 + n2;
  for (; i < total; i += stride) {
    const float4* s; ushort4* d; int j = i;
    if (j < n0)              { s = (const float4*)s0; d = (ushort4*)d0; }
    else if ((j -= n0) < n1) { s = (const float4*)s1; d = (ushort4*)d1; }
    else { j -= n1;            s = (const float4*)s2; d = (ushort4*)d2; }
    float4 v = s[j];
    ushort4 o;
    o.x = f2b(v.x); o.y = f2b(v.y); o.z = f2b(v.z); o.w = f2b(v.w);
    d[j] = o;
  }
}

// ---------------- GEMM: C[m,n] = sum_k A[m,k]*Bw[n,k] (+bias) ----------------
// BM=128 fixed; BN template. 1D grid + XCD chunked swizzle (bm major, bn
// minor within each XCD chunk -> A panels reused 32x inside one L2).
// __syncthreads() implicitly drains vmcnt before its barrier -> cross-wave
// global_load_lds publication is sound.
template<int OUTMODE, int BN>  // OUTMODE 0: bf16 out; 1: f32 out + bias
__global__ __launch_bounds__(256, 4) void k_gemm_bt(
    const u16* __restrict__ A, const u16* __restrict__ Bw,
    void* __restrict__ Cout, const float* __restrict__ bias,
    int M, int N, int K) {
  constexpr int NT = BN / 32;          // 16-col tiles per wave half
  constexpr int BCH = BN / 32;         // B staging chunks per thread
  __shared__ __align__(16) u16 As[128 * 64];
  __shared__ __align__(16) u16 Bs[BN * 64];
  const int tid = threadIdx.x;
  const int lane = tid & 63, w = tid >> 6;
  const int wr = w >> 1, wc = w & 1;
  const int g = lane >> 4, r16 = lane & 15, l7 = lane & 7;
  const int swz = xcd_swz(blockIdx.x, gridDim.x);
  const int nb = N / BN;
  const int bm = swz / nb, bn = swz % nb;
  const int co[2] = { (g ^ l7) * 8, ((4 | g) ^ l7) * 8 };

  f32x4 acc[4][NT] = {};
  const int LCl = w * 64 + lane;

  for (int k0 = 0; k0 < K; k0 += 64) {
    __syncthreads();
#pragma unroll
    for (int i = 0; i < 4; ++i) {
      int LC = i * 256 + LCl;
      int row = LC >> 3;
      int c = (LC & 7) ^ (row & 7);
      gload16(A + (bm * 128 + row) * K + k0 + c * 8, As + (i * 256 + w * 64) * 8);
    }
#pragma unroll
    for (int i = 0; i < BCH; ++i) {
      int LC = i * 256 + LCl;
      int row = LC >> 3;
      int c = (LC & 7) ^ (row & 7);
      gload16(Bw + (bn * BN + row) * K + k0 + c * 8, Bs + (i * 256 + w * 64) * 8);
    }
    __syncthreads();
#pragma unroll
    for (int s = 0; s < 2; ++s) {
      bf16x8 af[4], bfr[NT];
#pragma unroll
      for (int t = 0; t < 4; ++t)
        af[t] = *(const bf16x8*)&As[(wr * 64 + t * 16 + r16) * 64 + co[s]];
#pragma unroll
      for (int t = 0; t < NT; ++t)
        bfr[t] = *(const bf16x8*)&Bs[(wc * (BN / 2) + t * 16 + r16) * 64 + co[s]];
#pragma unroll
      for (int mt = 0; mt < 4; ++mt)
#pragma unroll
        for (int nt = 0; nt < NT; ++nt)
          acc[mt][nt] = __builtin_amdgcn_mfma_f32_16x16x32_bf16(
              af[mt], bfr[nt], acc[mt][nt], 0, 0, 0);
    }
  }

  const int mbase = bm * 128 + wr * 64 + g * 4;
  const int nbase = bn * BN + wc * (BN / 2) + r16;
  if (OUTMODE == 0) {
    u16* C = (u16*)Cout;
#pragma unroll
    for (int mt = 0; mt < 4; ++mt)
#pragma unroll
      for (int nt = 0; nt < NT; ++nt)
#pragma unroll
        for (int r = 0; r < 4; ++r)
          C[(mbase + mt * 16 + r) * N + nbase + nt * 16] = f2b(acc[mt][nt][r]);
  } else {
    float* C = (float*)Cout;
    float bv[NT];
#pragma unroll
    for (int nt = 0; nt < NT; ++nt) bv[nt] = bias[nbase + nt * 16];
#pragma unroll
    for (int mt = 0; mt < 4; ++mt)
#pragma unroll
      for (int nt = 0; nt < NT; ++nt)
#pragma unroll
        for (int r = 0; r < 4; ++r)
          C[(mbase + mt * 16 + r) * N + nbase + nt * 16] = acc[mt][nt][r] + bv[nt];
  }
}

// ---------------- RoPE + layout reorg ----------------
__global__ __launch_bounds__(256) void k_reorg(const u16* __restrict__ qkv,
    u16* __restrict__ Q, u16* __restrict__ K, u16* __restrict__ Vt) {
  __shared__ u16 vsh[64 * 72];
  const int bh = blockIdx.y, nt = blockIdx.x;
  const int b = bh >> 4, h = bh & 15;
  const int tid = threadIdx.x;
  const int nl = tid >> 2, c4 = tid & 3;
  const int n = nt * 64 + nl;
  const int srow = (b * 2048 + n) * 3072 + h * 64 + c4 * 16;

  float cs[8], sn[8];
#pragma unroll
  for (int p = 0; p < 8; ++p) {
    int c = c4 * 8 + p;
    float invf = exp2f(-0.41524101186092035f * (float)c);  // 10000^(-2c/64)
    float ang = (float)n * invf;
    sincosf(ang, &sn[p], &cs[p]);
  }

#pragma unroll
  for (int sel = 0; sel < 2; ++sel) {
    union { uint4 v[2]; u16 s[16]; } in, out;
    const uint4* sp = (const uint4*)(qkv + srow + sel * 1024);
    in.v[0] = sp[0]; in.v[1] = sp[1];
    const float scale = sel ? 1.0f : (0.125f * LOG2E);
#pragma unroll
    for (int p = 0; p < 8; ++p) {
      float xe = b2f(in.s[2 * p]), xo = b2f(in.s[2 * p + 1]);
      out.s[2 * p]     = f2b((xe * cs[p] - xo * sn[p]) * scale);
      out.s[2 * p + 1] = f2b((xe * sn[p] + xo * cs[p]) * scale);
    }
    u16* dp = (sel ? K : Q) + (bh * 2048 + n) * 64 + c4 * 16;
    ((uint4*)dp)[0] = out.v[0];
    ((uint4*)dp)[1] = out.v[1];
  }

  {
    const uint4* sp = (const uint4*)(qkv + srow + 2048);
    uint4 v0 = sp[0], v1 = sp[1];
    *(uint4*)&vsh[nl * 72 + c4 * 16] = v0;
    *(uint4*)&vsh[nl * 72 + c4 * 16 + 8] = v1;
  }
  __syncthreads();
  {
    const int d = tid >> 2, nc = tid & 3;
    union { uint4 v[2]; u16 s[16]; } o;
#pragma unroll
    for (int j = 0; j < 16; ++j) o.s[j] = vsh[(nc * 16 + j) * 72 + d];
    u16* dp = Vt + (bh * 64 + d) * 2048 + nt * 64 + nc * 16;
    ((uint4*)dp)[0] = o.v[0];
    ((uint4*)dp)[1] = o.v[1];
  }
}

// ---------------- Flash attention, 32x32 MFMA, kv-split waves ----------------
// Sync pattern (RACE LESSON, R10): per iter = stage(it+1) -> compute(it) ->
// s_waitcnt vmcnt(0) -> s_barrier. The vmcnt DRAIN MUST PRECEDE THE BARRIER:
// waves read LDS chunks staged by OTHER waves' async global_load_lds, and
// s_barrier orders instruction streams, not load completion.
// 1D grid + XCD chunked swizzle: each XCD owns 4 contiguous bh (K/V+Q
// working set 4MB -> fits its private L2; was scattered over all 32 bh).
__global__ __launch_bounds__(256, 4) void k_attn(
    const u16* __restrict__ Q, const u16* __restrict__ K,
    const u16* __restrict__ Vt, u16* __restrict__ Ao) {
  __shared__ __align__(16) u16 SH[4][64 * 64];  // [0..1] K dbuf, [2..3] V dbuf
  const int tid = threadIdx.x;
  const int lane = tid & 63, w = tid >> 6;
  const int l31 = lane & 31, hi = lane >> 5;
  const int qpair = w >> 1, kvh = w & 1;
  const int swz = xcd_swz(blockIdx.x, gridDim.x);
  const int bh = swz >> 5, qt = swz & 31;
  const int rr = l31 & 7;
  const int u = hi ^ (rr & 1);
  const int v = (rr >> 1) & 3;

  const int qrow = qt * 64 + qpair * 32 + l31;
  const u16* Qb = Q + (bh * 2048 + qrow) * 64 + 8 * hi;
  bf16x8 qf[4];
#pragma unroll
  for (int ks = 0; ks < 4; ++ks) qf[ks] = *(const bf16x8*)(Qb + 16 * ks);

  float z0 = 0.f;
  asm volatile("" : "+v"(z0));
  f32x16 zv;
#pragma unroll
  for (int r = 0; r < 16; ++r) zv[r] = z0;

  const u16 *kg0, *kg1, *vg0, *vg1;
  {
    int LC = tid, row = LC >> 3, c = (LC & 7) ^ (row & 7);
    kg0 = K + (bh * 2048 + row) * 64 + c * 8;
    vg0 = Vt + (bh * 64 + row) * 2048 + c * 8;
    int LC1 = 256 + tid, row1 = LC1 >> 3, c1 = (LC1 & 7) ^ (row1 & 7);
    kg1 = K + (bh * 2048 + row1) * 64 + c1 * 8;
    vg1 = Vt + (bh * 64 + row1) * 2048 + c1 * 8;
  }

  const int krowK = (kvh * 32 + l31) * 128;
  const int vrow0 = l31 * 128, vrow1 = (32 + l31) * 128;

  f32x16 acc0 = {}, acc1 = {};
  float lrun = 0.f;

  // prologue: stage tile 0 into buf 0, drain, publish
  gload16(kg0, SH[0] + tid * 8);
  gload16(kg1, SH[0] + (256 + tid) * 8);
  gload16(vg0, SH[2] + tid * 8);
  gload16(vg1, SH[2] + (256 + tid) * 8);
  kg0 += 4096; kg1 += 4096; vg0 += 64; vg1 += 64;
  asm volatile("s_waitcnt vmcnt(0)" ::: "memory");
  __builtin_amdgcn_s_barrier();

#pragma unroll 2
  for (int it = 0; it < 32; ++it) {
    const int cur = it & 1;
    if (it < 31) {  // issue next-tile stage first; lands under this compute
      gload16(kg0, SH[cur ^ 1] + tid * 8);
      gload16(kg1, SH[cur ^ 1] + (256 + tid) * 8);
      gload16(vg0, SH[2 + (cur ^ 1)] + tid * 8);
      gload16(vg1, SH[2 + (cur ^ 1)] + (256 + tid) * 8);
      kg0 += 4096; kg1 += 4096; vg0 += 64; vg1 += 64;
    }

    const char* Kb = (const char*)SH[cur];
    const char* Vb = (const char*)SH[2 + cur];

    f32x16 st;
    __builtin_amdgcn_s_setprio(1);
    {
      const int coff = (2 * v + u) << 4;
      bf16x8 ka = *(const bf16x8*)(Kb + krowK + coff);
      st = mfma32(ka, qf[0], zv);
    }
#pragma unroll
    for (int ks = 1; ks < 4; ++ks) {
      const int coff = (2 * (ks ^ v) + u) << 4;
      bf16x8 ka = *(const bf16x8*)(Kb + krowK + coff);
      st = mfma32(ka, qf[ks], st);
    }
    __builtin_amdgcn_s_setprio(0);

    float ls[4];
    u32 W[4][2];
#pragma unroll
    for (int s = 0; s < 4; ++s) {
      float pa = ex2(st[4 * s + 0]);
      float pb = ex2(st[4 * s + 1]);
      float pc = ex2(st[4 * s + 2]);
      float pd = ex2(st[4 * s + 3]);
      ls[s] = (pa + pb) + (pc + pd);
      W[s][0] = pk2(pa, pb);
      W[s][1] = pk2(pc, pd);
    }
    lrun += (ls[0] + ls[1]) + (ls[2] + ls[3]);

    __builtin_amdgcn_s_setprio(1);
#pragma unroll
    for (int ku = 0; ku < 2; ++ku) {
      u32 a0 = W[2 * ku][0], b0 = W[2 * ku + 1][0];
      u32 a1 = W[2 * ku][1], b1 = W[2 * ku + 1][1];
      asm volatile("v_permlane32_swap_b32 %0, %1" : "+&v"(a0), "+v"(b0));
      asm volatile("v_permlane32_swap_b32 %0, %1" : "+&v"(a1), "+v"(b1));
      union { u32 wd[4]; bf16x8 v8; } pbu;
      pbu.wd[0] = a0; pbu.wd[1] = a1; pbu.wd[2] = b0; pbu.wd[3] = b1;
      const int j = 2 * kvh + ku;
      const int coff = (2 * (j ^ v) + u) << 4;
      bf16x8 va0 = *(const bf16x8*)(Vb + vrow0 + coff);
      bf16x8 va1 = *(const bf16x8*)(Vb + vrow1 + coff);
      acc0 = mfma32(va0, pbu.v8, acc0);
      acc1 = mfma32(va1, pbu.v8, acc1);
    }
    __builtin_amdgcn_s_setprio(0);

    // drain my stage loads, THEN publish via barrier (race-free ordering)
    asm volatile("s_waitcnt vmcnt(0)" ::: "memory");
    __builtin_amdgcn_s_barrier();
  }

  // ---- epilogue: reduce the two kv-half waves of each qpair via LDS ----
  float* FS = (float*)SH;
  const int sbase = (qpair * 64 + lane) * 33;
  if (kvh == 1) {
#pragma unroll
    for (int r = 0; r < 16; ++r) {
      FS[sbase + r] = acc0[r];
      FS[sbase + 16 + r] = acc1[r];
    }
    FS[8000 + qpair * 64 + lane] = lrun;
  }
  __syncthreads();
  if (kvh == 0) {
#pragma unroll
    for (int r = 0; r < 16; ++r) {
      acc0[r] += FS[sbase + r];
      acc1[r] += FS[sbase + 16 + r];
    }
    lrun += FS[8000 + qpair * 64 + lane];
    float lo = __shfl_xor(lrun, 32);
    float sc = rcp(lrun + lo);

    const int m = (bh >> 4) * 2048 + qrow;
    u16* orow = Ao + m * 1024 + (bh & 15) * 64 + 4 * hi;
#pragma unroll
    for (int s = 0; s < 4; ++s) {
      uint2 o0, o1;
      o0.x = pk2(acc0[4 * s + 0] * sc, acc0[4 * s + 1] * sc);
      o0.y = pk2(acc0[4 * s + 2] * sc, acc0[4 * s + 3] * sc);
      *(uint2*)(orow + 8 * s) = o0;
      o1.x = pk2(acc1[4 * s + 0] * sc, acc1[4 * s + 1] * sc);
      o1.y = pk2(acc1[4 * s + 2] * sc, acc1[4 * s + 3] * sc);
      *(uint2*)(orow + 32 + 8 * s) = o1;
    }
  }
}

extern "C" void kernel_launch(void* const* d_in, const int* in_sizes, int n_in,
                              void* d_out, int out_size, void* d_ws, size_t ws_size,
                              hipStream_t stream) {
  (void)in_sizes; (void)n_in; (void)out_size; (void)ws_size;
  const float* x      = (const float*)d_in[0];
  const float* w_qkv  = (const float*)d_in[1];
  const float* w_proj = (const float*)d_in[2];
  const float* b_proj = (const float*)d_in[3];
  float* out = (float*)d_out;

  char* W = (char*)d_ws;
  u16* xb     = (u16*)(W + 0);              // 4096x1024 bf16 (8 MB)
  u16* attnb  = (u16*)(W + 0);              // reuse xb region after GEMM1
  u16* wqkvb  = (u16*)(W + (8u  << 20));    // 3072x1024 bf16 (6 MB)
  u16* wprojb = (u16*)(W + (14u << 20));    // 1024x1024 bf16 (2 MB)
  u16* qkvb   = (u16*)(W + (16u << 20));    // 4096x3072 bf16 (24 MB)
  u16* Qws    = (u16*)(W + (40u << 20));    // 32x2048x64 bf16 (8 MB)
  u16* Kws    = (u16*)(W + (48u << 20));    // 32x2048x64 bf16 (8 MB)
  u16* Vtws   = (u16*)(W + (56u << 20));    // 32x64x2048 bf16 (8 MB)

  k_cvt3<<<2048, 256, 0, stream>>>(x, xb, (4096 * 1024) / 4,
                                   w_qkv, wqkvb, (3072 * 1024) / 4,
                                   w_proj, wprojb, (1024 * 1024) / 4);
  k_gemm_bt<0, 96><<<1024, 256, 0, stream>>>(
      xb, wqkvb, (void*)qkvb, nullptr, 4096, 3072, 1024);
  k_reorg<<<dim3(32, 32), 256, 0, stream>>>(qkvb, Qws, Kws, Vtws);
  k_attn<<<1024, 256, 0, stream>>>(Qws, Kws, Vtws, attnb);
  k_gemm_bt<1, 32><<<1024, 256, 0, stream>>>(
      attnb, wprojb, (void*)out, b_proj, 4096, 1024, 1024);
}